// Round 2
// baseline (848.645 us; speedup 1.0000x reference)
//
#include <hip/hip_runtime.h>

typedef float f4 __attribute__((ext_vector_type(4)));
typedef float f32x4 __attribute__((ext_vector_type(4)));
typedef unsigned short ushort8_t __attribute__((ext_vector_type(8)));
typedef short s16x8 __attribute__((ext_vector_type(8)));   // bf16 fragment, guide-verified form

// ---- problem constants ----
#define NB   8
#define NP   120
#define NE   960          // B*P
#define NL   128
#define NH   768
#define NSEN 16

// ---- output offsets (in floats) ----
#define OFF_MIX      0                    // (960,2,768)
#define OFF_FINAL    1474560              // (8,16,768)
#define OFF_CLSMAT   1572864              // (8,16,16,768)
#define OFF_CLSSC    3145728              // (960,2)
#define OFF_SCMAT    3147648              // (8,16,16,2)
#define OFF_H1MAT    3151744
#define OFF_H2MAT    3155840
#define OUT_TOTAL    3159936

__device__ __forceinline__ unsigned short f2bf(float f) {
  unsigned int u = __builtin_bit_cast(unsigned int, f);
  u += 0x7fffu + ((u >> 16) & 1u);          // RNE
  return (unsigned short)(u >> 16);
}

__device__ __forceinline__ float fast_tanh(float x) {
  float e = __expf(2.0f * x);
  return 1.0f - 2.0f * __builtin_amdgcn_rcpf(e + 1.0f);
}

// ============ kernel 1: W_st (k,n) f32 -> Wt (n,k) bf16 ============
__global__ __launch_bounds__(256) void wt_kernel(const float* __restrict__ W,
                                                 unsigned short* __restrict__ Wt) {
  __shared__ float t[32][33];
  int bid = blockIdx.x;
  int bk = bid % 24, bn = bid / 24;
  int tx = threadIdx.x & 31, ty = threadIdx.x >> 5;
#pragma unroll
  for (int i = 0; i < 4; ++i)
    t[ty + i * 8][tx] = W[(size_t)(bk * 32 + ty + i * 8) * NH + bn * 32 + tx];
  __syncthreads();
#pragma unroll
  for (int i = 0; i < 4; ++i)
    Wt[(size_t)(bn * 32 + ty + i * 8) * NH + bk * 32 + tx] = f2bf(t[tx][ty + i * 8]);
}

// ============ kernel 2: fused tok_score GEMM ============
// per block: 64 rows of flattened (E*L, H); A resident in LDS (bf16, swizzled);
// B = Wt streamed in 256(n) x 32(k) double-buffered tiles via global_load_lds.
__device__ __forceinline__ void stage_b(const unsigned short* __restrict__ Wt,
                                        unsigned short* bsbuf,
                                        int nc, int kt, int w, int tid) {
#pragma unroll
  for (int j = 0; j < 2; ++j) {
    int q = tid + j * 512;                 // 16B-chunk id, 0..1023
    int n = q >> 2, c4 = q & 3;
    int sc4 = c4 ^ ((n >> 1) & 3);         // pre-swizzled global source (m173)
    const unsigned short* gp = Wt + (size_t)(nc * 256 + n) * NH + kt * 32 + sc4 * 8;
    unsigned short* lp = bsbuf + (size_t)(w * 64 + j * 512) * 8;  // wave-uniform base
    __builtin_amdgcn_global_load_lds((const __attribute__((address_space(1))) void*)gp,
                                     (__attribute__((address_space(3))) void*)lp, 16, 0, 0);
  }
}

__global__ __launch_bounds__(512, 1) void tok_kernel(
    const float* __restrict__ seq, const int* __restrict__ sep,
    const unsigned short* __restrict__ Wt, const float* __restrict__ b_st,
    const float* __restrict__ w_st2, const float* __restrict__ b_st2,
    float* __restrict__ tok_out) {
  int blk = blockIdx.x;
  int e = blk >> 1, half = blk & 1;
  if (half && sep[e * 2 + 1] < 64) return;   // rows 64..127 never read downstream

  __shared__ unsigned short As[64 * NH];      // 96KB, swizzled
  __shared__ unsigned short Bs[2][256 * 32];  // 2 x 16KB, swizzled
  __shared__ float s_score[64];

  int tid = threadIdx.x;
  int lane = tid & 63, w = tid >> 6;          // 8 waves
  int wm = w >> 2, wn = w & 3;                // wave tile 32(m) x 64(n)
  int lrow = lane & 15, lgrp = lane >> 4;

  if (tid < 64) s_score[tid] = 0.0f;

  // ---- A staging: 64 x 768 f32 -> bf16 LDS (swizzle: byte ^= (r&7)<<4)
  const float* Ab = seq + (size_t)(e * NL + half * 64) * NH;
#pragma unroll
  for (int i = 0; i < 12; ++i) {
    int c = tid + i * 512;                    // 6144 chunks of 8 floats
    int r = c / 96, k8 = c - r * 96;
    const f4* g = (const f4*)(Ab + (size_t)r * NH + k8 * 8);
    f4 f0 = g[0], f1 = g[1];
    ushort8_t u;
    u[0] = f2bf(f0[0]); u[1] = f2bf(f0[1]); u[2] = f2bf(f0[2]); u[3] = f2bf(f0[3]);
    u[4] = f2bf(f1[0]); u[5] = f2bf(f1[1]); u[6] = f2bf(f1[2]); u[7] = f2bf(f1[3]);
    int byteo = r * 1536 + ((k8 * 16) ^ ((r & 7) << 4));
    *(ushort8_t*)((char*)As + byteo) = u;
  }

  stage_b(Wt, Bs[0], 0, 0, w, tid);
  __syncthreads();

  f32x4 zero4 = {0.0f, 0.0f, 0.0f, 0.0f};
  f32x4 acc[2][4];
#pragma unroll
  for (int mf = 0; mf < 2; ++mf)
#pragma unroll
    for (int nf = 0; nf < 4; ++nf) acc[mf][nf] = zero4;
  float sp[2][4] = {{0, 0, 0, 0}, {0, 0, 0, 0}};

  int buf = 0;
  for (int nc = 0; nc < 3; ++nc) {
    for (int kt = 0; kt < 24; ++kt) {
      int nn = nc, nk = kt + 1;
      if (nk == 24) { nk = 0; ++nn; }
      if (nn < 3) stage_b(Wt, Bs[buf ^ 1], nn, nk, w, tid);

      s16x8 a[2], bb[4];
#pragma unroll
      for (int mf = 0; mf < 2; ++mf) {
        int r = wm * 32 + mf * 16 + lrow;
        int byteo = r * 1536 + (((kt * 32 + lgrp * 8) * 2) ^ ((r & 7) << 4));
        a[mf] = *(const s16x8*)((const char*)As + byteo);
      }
#pragma unroll
      for (int nf = 0; nf < 4; ++nf) {
        int nl = wn * 64 + nf * 16 + lrow;
        int byteo = nl * 64 + ((lgrp * 16) ^ (((nl >> 1) & 3) << 4));
        bb[nf] = *(const s16x8*)((const char*)Bs[buf] + byteo);
      }
#pragma unroll
      for (int mf = 0; mf < 2; ++mf)
#pragma unroll
        for (int nf = 0; nf < 4; ++nf)
          acc[mf][nf] = __builtin_amdgcn_mfma_f32_16x16x32_bf16(a[mf], bb[nf], acc[mf][nf], 0, 0, 0);

      __syncthreads();
      buf ^= 1;
    }
    // ---- fused epilogue for this n-chunk: score += tanh(acc+bias)*w2
#pragma unroll
    for (int mf = 0; mf < 2; ++mf)
#pragma unroll
      for (int nf = 0; nf < 4; ++nf) {
        int col = nc * 256 + wn * 64 + nf * 16 + lrow;
        float bias = b_st[col], w2 = w_st2[col];
#pragma unroll
        for (int r = 0; r < 4; ++r)
          sp[mf][r] += fast_tanh(acc[mf][nf][r] + bias) * w2;
        acc[mf][nf] = zero4;
      }
  }

  // reduce over the 16 column-lanes sharing lgrp, then across the 4 wn-waves
#pragma unroll
  for (int mf = 0; mf < 2; ++mf)
#pragma unroll
    for (int r = 0; r < 4; ++r) {
      float v = sp[mf][r];
      v += __shfl_xor(v, 1); v += __shfl_xor(v, 2);
      v += __shfl_xor(v, 4); v += __shfl_xor(v, 8);
      if (lrow == 0) atomicAdd(&s_score[wm * 32 + mf * 16 + lgrp * 4 + r], v);
    }
  __syncthreads();
  if (tid < 64) tok_out[(size_t)blk * 64 + tid] = s_score[tid] + b_st2[0];
}

// ============ kernel 3: per-e two-segment softmax + mix ============
__global__ __launch_bounds__(256) void mix_kernel(
    const float* __restrict__ seq, const float* __restrict__ tok,
    const int* __restrict__ sep, float* __restrict__ out) {
  int e = blockIdx.x;
  int sep0 = sep[2 * e], sep1 = sep[2 * e + 1];
  __shared__ float att[2][128];
  int tid = threadIdx.x;
  int lane = tid & 63, w = tid >> 6;

  att[tid >> 7][tid & 127] = 0.0f;
  __syncthreads();

  if (w < 2) {   // wave0: segment [1,sep0]; wave1: (sep0,sep1]
    int lo = (w == 0) ? 1 : sep0 + 1;
    int hi = (w == 0) ? sep0 : sep1;
    int l0 = lo + lane, l1 = lo + 64 + lane;
    float v0 = (l0 <= hi) ? tok[(size_t)e * NL + l0] : -1e30f;
    float v1 = (l1 <= hi) ? tok[(size_t)e * NL + l1] : -1e30f;
    float m = fmaxf(v0, v1);
#pragma unroll
    for (int d = 1; d < 64; d <<= 1) m = fmaxf(m, __shfl_xor(m, d));
    float e0 = 0.0f, e1 = 0.0f, s = 0.0f;
    if (l0 <= hi) { e0 = __expf(v0 - m); s += e0; }
    if (l1 <= hi) { e1 = __expf(v1 - m); s += e1; }
#pragma unroll
    for (int d = 1; d < 64; d <<= 1) s += __shfl_xor(s, d);
    float inv = 1.0f / s;
    if (l0 <= hi) att[w][l0] = e0 * inv;
    if (l1 <= hi) att[w][l1] = e1 * inv;
  }
  __syncthreads();

  float a00 = 0, a01 = 0, a02 = 0, a10 = 0, a11 = 0, a12 = 0;
  const float* S = seq + (size_t)e * (NL * NH);
  for (int l = 1; l <= sep1; ++l) {
    float w0 = att[0][l], w1 = att[1][l];
    float v0 = S[(size_t)l * NH + tid];
    float v1 = S[(size_t)l * NH + tid + 256];
    float v2 = S[(size_t)l * NH + tid + 512];
    a00 = fmaf(w0, v0, a00); a01 = fmaf(w0, v1, a01); a02 = fmaf(w0, v2, a02);
    a10 = fmaf(w1, v0, a10); a11 = fmaf(w1, v1, a11); a12 = fmaf(w1, v2, a12);
  }
  float* M = out + OFF_MIX + (size_t)e * (2 * NH);
  M[tid] = a00; M[tid + 256] = a01; M[tid + 512] = a02;
  M[NH + tid] = a10; M[NH + tid + 256] = a11; M[NH + tid + 512] = a12;
}

// ============ kernel 4: cls projections + scatters ============
__global__ __launch_bounds__(256) void cls_kernel(
    const float* __restrict__ cls, const int* __restrict__ pairs,
    const float* __restrict__ Wpw, const float* __restrict__ bpw,
    const float* __restrict__ Wh1, const float* __restrict__ bh1,
    const float* __restrict__ Wh2, const float* __restrict__ bh2,
    float* __restrict__ out) {
  int e = blockIdx.x;
  int tid = threadIdx.x;
  const float* c = cls + (size_t)e * NH;
  float p[6] = {0, 0, 0, 0, 0, 0};
#pragma unroll
  for (int i = 0; i < 3; ++i) {
    int k = tid + i * 256;
    float x = c[k];
    p[0] += x * Wpw[k * 2]; p[1] += x * Wpw[k * 2 + 1];
    p[2] += x * Wh1[k * 2]; p[3] += x * Wh1[k * 2 + 1];
    p[4] += x * Wh2[k * 2]; p[5] += x * Wh2[k * 2 + 1];
  }
  __shared__ float red[4][6];
  int lane = tid & 63, w = tid >> 6;
#pragma unroll
  for (int j = 0; j < 6; ++j) {
    float v = p[j];
#pragma unroll
    for (int d = 1; d < 64; d <<= 1) v += __shfl_xor(v, d);
    if (lane == 0) red[w][j] = v;
  }
  __syncthreads();
  int b = e / NP, pp = e - b * NP;
  int p0 = pairs[b * (NP * 2) + pp * 2], p1 = pairs[b * (NP * 2) + pp * 2 + 1];
  size_t midx = (size_t)b * 256 + p0 * 16 + p1;
  if (tid < 6) {
    float v = red[0][tid] + red[1][tid] + red[2][tid] + red[3][tid];
    int mat = tid >> 1, j = tid & 1;
    if (mat == 0) {
      v += bpw[j];
      out[OFF_CLSSC + (size_t)e * 2 + j] = v;
      out[OFF_SCMAT + midx * 2 + j] = v;
    } else if (mat == 1) {
      out[OFF_H1MAT + midx * 2 + j] = v + bh1[j];
    } else {
      out[OFF_H2MAT + midx * 2 + j] = v + bh2[j];
    }
  }
  float* dst = out + OFF_CLSMAT + midx * NH;
  dst[tid] = c[tid]; dst[tid + 256] = c[tid + 256]; dst[tid + 512] = c[tid + 512];
}

// ============ kernel 5: final_seq (graph pooling) ============
__global__ __launch_bounds__(256) void final_kernel(
    const float* __restrict__ mix, const int* __restrict__ pairs,
    const float* __restrict__ wlin, float* __restrict__ outf) {
  int b = blockIdx.x >> 4, n = blockIdx.x & 15;
  __shared__ int rows[16];
  __shared__ float q[16];
  __shared__ int cnt;
  int tid = threadIdx.x;
  if (tid == 0) cnt = 0;
  __syncthreads();
  if (tid < NP) {
    int p0 = pairs[b * (NP * 2) + tid * 2], p1 = pairs[b * (NP * 2) + tid * 2 + 1];
    if (p0 == n) { int i = atomicAdd(&cnt, 1); if (i < 16) rows[i] = (b * NP + tid) * 2; }
    if (p1 == n) { int i = atomicAdd(&cnt, 1); if (i < 16) rows[i] = (b * NP + tid) * 2 + 1; }
  }
  __syncthreads();
  int NC = cnt < 16 ? cnt : 16;
  int lane = tid & 63, w = tid >> 6;
  for (int j = w; j < NC; j += 4) {
    const float* m = mix + (size_t)rows[j] * NH;
    float s = 0;
    for (int k = lane; k < NH; k += 64) s += m[k] * wlin[k];
#pragma unroll
    for (int d = 1; d < 64; d <<= 1) s += __shfl_xor(s, d);
    if (lane == 0) q[j] = s;
  }
  __syncthreads();
  float mx = -1e30f;
  for (int j = 0; j < NC; ++j) mx = fmaxf(mx, q[j]);
  float den = 0;
  for (int j = 0; j < NC; ++j) den += __expf(q[j] - mx);
  float inv = 1.0f / den;
  float a0 = 0, a1 = 0, a2 = 0;
  for (int j = 0; j < NC; ++j) {
    float wgt = __expf(q[j] - mx) * inv;
    const float* m = mix + (size_t)rows[j] * NH;
    a0 += wgt * m[tid]; a1 += wgt * m[tid + 256]; a2 += wgt * m[tid + 512];
  }
  float* f = outf + ((size_t)b * 16 + n) * NH;
  f[tid] = a0; f[tid + 256] = a1; f[tid + 512] = a2;
}

extern "C" void kernel_launch(void* const* d_in, const int* in_sizes, int n_in,
                              void* d_out, int out_size, void* d_ws, size_t ws_size,
                              hipStream_t stream) {
  (void)in_sizes; (void)n_in; (void)out_size; (void)ws_size;
  const float* seq   = (const float*)d_in[0];
  const int*   pairs = (const int*)d_in[1];
  const int*   sep   = (const int*)d_in[4];
  const float* cls   = (const float*)d_in[6];
  const float* W_st  = (const float*)d_in[7];
  const float* b_st  = (const float*)d_in[8];
  const float* w_st2 = (const float*)d_in[9];
  const float* b_st2 = (const float*)d_in[10];
  const float* wlin2 = (const float*)d_in[11];
  const float* W_pw  = (const float*)d_in[12];
  const float* b_pw  = (const float*)d_in[13];
  const float* W_h1  = (const float*)d_in[14];
  const float* b_h1  = (const float*)d_in[15];
  const float* W_h2  = (const float*)d_in[16];
  const float* b_h2  = (const float*)d_in[17];
  float* out = (float*)d_out;

  unsigned short* Wt = (unsigned short*)d_ws;                       // 768*768 bf16
  float* tok = (float*)((char*)d_ws + (size_t)NH * NH * 2);         // 122880 f32

  // zero the scatter-target region (cls_out_mat .. h2_mat)
  hipMemsetAsync(out + OFF_CLSMAT, 0, (size_t)(OUT_TOTAL - OFF_CLSMAT) * 4, stream);

  wt_kernel<<<576, 256, 0, stream>>>(W_st, Wt);
  tok_kernel<<<NE * 2, 512, 0, stream>>>(seq, sep, Wt, b_st, w_st2, b_st2, tok);
  mix_kernel<<<NE, 256, 0, stream>>>(seq, tok, sep, out);
  cls_kernel<<<NE, 256, 0, stream>>>(cls, pairs, W_pw, b_pw, W_h1, b_h1, W_h2, b_h2, out);
  final_kernel<<<128, 256, 0, stream>>>(out + OFF_MIX, pairs, wlin2, out + OFF_FINAL);
}